// Round 6
// baseline (339.320 us; speedup 1.0000x reference)
//
#include <hip/hip_runtime.h>
#include <math.h>

#define NB 8192
#define D 768
#define EPSV 1e-8f
#define BT 256
#define BK 64
#define NT (NB / BT)                 // 32 tiles per dim
#define NBLK (NT * (NT + 1) / 2)     // 528 triangular blocks

typedef float f32x4 __attribute__((ext_vector_type(4)));
typedef short s16x8 __attribute__((ext_vector_type(8)));

#define BARM() asm volatile("s_barrier" ::: "memory")
#define LGKM0() asm volatile("s_waitcnt lgkmcnt(0)" ::: "memory")
#define VMC(n) asm volatile("s_waitcnt vmcnt(" #n ")" ::: "memory")

// ---------- helpers ----------
__device__ __forceinline__ unsigned short f2bf(float f) {
  unsigned u = __float_as_uint(f);
  u += 0x7fffu + ((u >> 16) & 1u);
  return (unsigned short)(u >> 16);
}
__device__ __forceinline__ unsigned encf(float f) {
  unsigned u = __float_as_uint(f);
  return (u & 0x80000000u) ? ~u : (u | 0x80000000u);
}
__device__ __forceinline__ float decf(unsigned u) {
  return (u & 0x80000000u) ? __uint_as_float(u & 0x7fffffffu)
                           : __uint_as_float(~u);
}
// Accumulator constrained to AGPR ("+a"): with "+v" the allocator parked acc
// in AGPRs anyway (VGPR pressure) and wrapped EVERY mfma in v_accvgpr_read/
// write pairs — ~128 moves/wave/phase, the round-3..5 16%-MfmaUtil killer.
__device__ __forceinline__ void mfma_bf16(f32x4& c, s16x8 a, s16x8 b) {
  asm("v_mfma_f32_16x16x32_bf16 %0, %1, %2, %0" : "+a"(c) : "v"(a), "v"(b));
}

// stage one 128x64 half-tile: linear LDS dest (global_load_lds requirement),
// inverse-swizzled global source (rule #21). 2 wave-loads per half-tile.
__device__ __forceinline__ void stage_half(const unsigned short* __restrict__ xb,
                                           unsigned short* lds, int rbase,
                                           int row0, int k0, int w, int l) {
#pragma unroll
  for (int i = 0; i < 2; ++i) {
    const int pu = i * 8192 + w * 1024;        // wave-uniform byte offset
    const int p = pu + l * 16;                 // this lane's linear byte
    const int sp = p ^ (((p >> 9) & 1) << 5);  // st_16x32 involution
    const unsigned short* src =
        xb + (size_t)(row0 + (sp >> 7)) * D + k0 + ((sp & 127) >> 1);
    __builtin_amdgcn_global_load_lds(
        (const __attribute__((address_space(1))) void*)src,
        (__attribute__((address_space(3))) void*)(lds + rbase + (pu >> 1)), 16,
        0, 0);
  }
}

__device__ __forceinline__ s16x8 ldfrag(const unsigned short* lds, int rbase,
                                        int r, int c) {
  int b = (r << 7) | (c << 1);
  b ^= ((b >> 9) & 1) << 5;  // same XOR on read side
  return *(const s16x8*)(lds + rbase + (b >> 1));
}

// ---------- kernel 1: L2-normalize rows, write bf16 ----------
__global__ __launch_bounds__(256) void normalize_kernel(
    const float* __restrict__ in, unsigned short* __restrict__ xb) {
  const int row = blockIdx.x;
  const int t = threadIdx.x;
  float4 v = make_float4(0.f, 0.f, 0.f, 0.f);
  const float4* rp = (const float4*)(in + (size_t)row * D);
  if (t < D / 4) v = rp[t];
  float ss = v.x * v.x + v.y * v.y + v.z * v.z + v.w * v.w;
#pragma unroll
  for (int m = 1; m < 64; m <<= 1) ss += __shfl_xor(ss, m, 64);
  __shared__ float wss[4];
  if ((t & 63) == 0) wss[t >> 6] = ss;
  __syncthreads();
  float tot = wss[0] + wss[1] + wss[2] + wss[3];
  float inv = 1.0f / fmaxf(sqrtf(tot), EPSV);
  if (t < D / 4) {
    ushort4 o;
    o.x = f2bf(v.x * inv);
    o.y = f2bf(v.y * inv);
    o.z = f2bf(v.z * inv);
    o.w = f2bf(v.w * inv);
    *(ushort4*)(xb + (size_t)row * D + t * 4) = o;
  }
}

// ---------- kernel 2: 256^2 8-phase triangular Gram + fused row/col max ----
// LDS: 2 buf x {A0,A1,B0,B1} x 16KB = 128KB. 8 waves (2Mx4N), acc 128x64/wave.
__global__ void __attribute__((amdgpu_flat_work_group_size(512, 512)))
__attribute__((amdgpu_waves_per_eu(1, 2)))
gemm_max_kernel(const unsigned short* __restrict__ xb,
                unsigned* __restrict__ gmax) {
  __shared__ unsigned short lds[65536];
  const int t = threadIdx.x;
  const int w = t >> 6, l = t & 63;
  const int wm = w >> 2, wn = w & 3;

  const int bid = blockIdx.x;
  const int widx = (bid & 7) * (NBLK / 8) + (bid >> 3);  // XCD swizzle
  int brow = (int)((sqrtf(8.0f * (float)widx + 1.0f) - 1.0f) * 0.5f);
  while ((brow + 1) * (brow + 2) / 2 <= widx) ++brow;
  while (brow * (brow + 1) / 2 > widx) --brow;
  const int bcol = widx - brow * (brow + 1) / 2;
  const bool diag = (brow == bcol);
  const int arow = brow * BT, acol = bcol * BT;

  f32x4 acc[8][4] = {};

  const int AB = wm * 8192;                // + buf : this wave's A half
  const int BB = 16384 + (wn >> 1) * 8192; // + buf : this wave's B half

#define RD_B(buf)                                                             \
  {                                                                           \
    _Pragma("unroll") for (int n = 0; n < 4; ++n) _Pragma("unroll") for (     \
        int kk = 0; kk < 2;                                                   \
        ++kk) bfr[n * 2 + kk] = ldfrag(lds, (buf) + BB,                       \
                                       (wn & 1) * 64 + n * 16 + (l & 15),     \
                                       kk * 32 + (l >> 4) * 8);               \
  }
#define RD_A(buf, dst, m0)                                                    \
  {                                                                           \
    _Pragma("unroll") for (int mm = 0; mm < 2; ++mm) _Pragma("unroll") for (  \
        int kk = 0; kk < 2;                                                   \
        ++kk) dst[mm * 2 + kk] = ldfrag(lds, (buf) + AB,                      \
                                        ((m0) + mm) * 16 + (l & 15),          \
                                        kk * 32 + (l >> 4) * 8);              \
  }
#define MFMA_Q(q, a)                                                          \
  {                                                                           \
    __builtin_amdgcn_s_setprio(1);                                            \
    _Pragma("unroll") for (int mm = 0; mm < 2; ++mm)                          \
        _Pragma("unroll") for (int n = 0; n < 4; ++n)                         \
            _Pragma("unroll") for (int kk = 0; kk < 2; ++kk)                  \
                mfma_bf16(acc[2 * (q) + mm][n], a[mm * 2 + kk],               \
                          bfr[n * 2 + kk]);                                   \
    __builtin_amdgcn_s_setprio(0);                                            \
  }

  // prologue: K-tile0 -> buf0 (4 half-tiles), K-tile1 -> buf1.{B0,B1,A0}
  stage_half(xb, lds, 0, arow, 0, w, l);
  stage_half(xb, lds, 8192, arow + 128, 0, w, l);
  stage_half(xb, lds, 16384, acol, 0, w, l);
  stage_half(xb, lds, 24576, acol + 128, 0, w, l);
  VMC(4);
  stage_half(xb, lds, 32768 + 16384, acol, 64, w, l);
  stage_half(xb, lds, 32768 + 24576, acol + 128, 64, w, l);
  stage_half(xb, lds, 32768, arow, 64, w, l);
  VMC(6);
  BARM();

#pragma unroll 1
  for (int itn = 0; itn < 6; ++itn) {
    const int kC1 = 2 * itn + 1;
    const int kS0 = (2 * itn + 2 < 12) ? 2 * itn + 2 : 11;  // buf0 target
    const int kS1 = (2 * itn + 3 < 12) ? 2 * itn + 3 : 11;  // buf1 target
    s16x8 bfr[8], aA[4], aB[4], aC[4], aD[4];

    // ---- phases 1-4: compute K-tile 2t (buf0) ----
    RD_B(0);
    RD_A(0, aA, 0);
    stage_half(xb, lds, 32768 + 8192, arow + 128, kC1 * 64, w, l);  // buf1.A1
    BARM();
    LGKM0();
    MFMA_Q(0, aA);
    BARM();

    RD_A(0, aB, 2);
    RD_A(0, aC, 4);
    stage_half(xb, lds, 16384, acol, kS0 * 64, w, l);  // buf0.B0
    BARM();
    LGKM0();
    MFMA_Q(1, aB);
    BARM();

    RD_A(0, aD, 6);
    stage_half(xb, lds, 24576, acol + 128, kS0 * 64, w, l);  // buf0.B1
    BARM();
    LGKM0();
    MFMA_Q(2, aC);
    BARM();

    stage_half(xb, lds, 0, arow, kS0 * 64, w, l);  // buf0.A0
    BARM();
    LGKM0();
    MFMA_Q(3, aD);
    VMC(6);
    BARM();

    // ---- phases 5-8: compute K-tile 2t+1 (buf1) ----
    RD_B(32768);
    RD_A(32768, aA, 0);
    stage_half(xb, lds, 8192, arow + 128, kS0 * 64, w, l);  // buf0.A1
    BARM();
    LGKM0();
    MFMA_Q(0, aA);
    BARM();

    RD_A(32768, aB, 2);
    RD_A(32768, aC, 4);
    stage_half(xb, lds, 32768 + 16384, acol, kS1 * 64, w, l);  // buf1.B0
    BARM();
    LGKM0();
    MFMA_Q(1, aB);
    BARM();

    RD_A(32768, aD, 6);
    stage_half(xb, lds, 32768 + 24576, acol + 128, kS1 * 64, w, l);  // buf1.B1
    BARM();
    LGKM0();
    MFMA_Q(2, aC);
    BARM();

    stage_half(xb, lds, 32768, arow, kS1 * 64, w, l);  // buf1.A0
    BARM();
    LGKM0();
    MFMA_Q(3, aD);
    VMC(6);
    BARM();
  }

  // ---- epilogue: fused max. C/D: col=lane&15, row=(lane>>4)*4+reg ----
  const int q4 = l >> 4, c0 = l & 15;
  const int rowbase = arow + wm * 128;
  const int colbase = acol + wn * 64;
#pragma unroll
  for (int m = 0; m < 8; ++m) {
#pragma unroll
    for (int reg = 0; reg < 4; ++reg) {
      const int grow = rowbase + m * 16 + q4 * 4 + reg;
      float v = -INFINITY;
#pragma unroll
      for (int n = 0; n < 4; ++n) {
        float val = acc[m][n][reg];
        if (diag && grow == colbase + n * 16 + c0) val = -1.0f;
        v = fmaxf(v, val);
      }
      v = fmaxf(v, __shfl_xor(v, 1));
      v = fmaxf(v, __shfl_xor(v, 2));
      v = fmaxf(v, __shfl_xor(v, 4));
      v = fmaxf(v, __shfl_xor(v, 8));
      if (c0 == 0) atomicMax(&gmax[grow], encf(v));
    }
  }
  if (!diag) {
#pragma unroll
    for (int n = 0; n < 4; ++n) {
      float v = -INFINITY;
#pragma unroll
      for (int m = 0; m < 8; ++m)
#pragma unroll
        for (int reg = 0; reg < 4; ++reg) v = fmaxf(v, acc[m][n][reg]);
      v = fmaxf(v, __shfl_xor(v, 16));
      v = fmaxf(v, __shfl_xor(v, 32));
      if (q4 == 0) atomicMax(&gmax[colbase + n * 16 + c0], encf(v));
    }
  }
  asm volatile("s_waitcnt vmcnt(0)" ::: "memory");  // drain trailing stages
}

// ---------- kernel 3: loss ----------
__global__ __launch_bounds__(1024) void loss_kernel(
    const unsigned* __restrict__ gmax, float* __restrict__ out) {
  const int t = threadIdx.x;
  float s = 0.f;
  for (int i = t; i < NB; i += 1024) {
    float dot = decf(gmax[i]);
    float d2 = fmaxf(2.0f - 2.0f * dot, 0.0f);
    s += logf(sqrtf(d2) + EPSV);
  }
#pragma unroll
  for (int m = 1; m < 64; m <<= 1) s += __shfl_xor(s, m, 64);
  __shared__ float wsum[16];
  if ((t & 63) == 0) wsum[t >> 6] = s;
  __syncthreads();
  if (t == 0) {
    float tot = 0.f;
#pragma unroll
    for (int i = 0; i < 16; ++i) tot += wsum[i];
    out[0] = -tot / (float)NB;
  }
}

// ---------- launch ----------
extern "C" void kernel_launch(void* const* d_in, const int* in_sizes, int n_in,
                              void* d_out, int out_size, void* d_ws,
                              size_t ws_size, hipStream_t stream) {
  const float* in = (const float*)d_in[0];
  float* out = (float*)d_out;
  unsigned* gmax = (unsigned*)d_ws;                             // 8192 u32
  unsigned short* xb = (unsigned short*)((char*)d_ws + 32768);  // bf16 x

  hipMemsetAsync(gmax, 0, NB * sizeof(unsigned), stream);
  normalize_kernel<<<NB, 256, 0, stream>>>(in, xb);
  gemm_max_kernel<<<NBLK, 512, 0, stream>>>(xb, gmax);
  loss_kernel<<<1, 1024, 0, stream>>>(gmax, out);
}

// Round 7
// 134.165 us; speedup vs baseline: 2.5291x; 2.5291x over previous
//
#include <hip/hip_runtime.h>
#include <math.h>

#define NB 8192
#define D 768
#define EPSV 1e-8f
#define BT 256
#define BK 64
#define NT (NB / BT)                 // 32 tiles per dim
#define NBLK (NT * (NT + 1) / 2)     // 528 triangular blocks

typedef float f32x4 __attribute__((ext_vector_type(4)));
typedef short s16x8 __attribute__((ext_vector_type(8)));

#define BARM() asm volatile("s_barrier" ::: "memory")
#define LGKM0() asm volatile("s_waitcnt lgkmcnt(0)" ::: "memory")
#define VMC(n) asm volatile("s_waitcnt vmcnt(" #n ")" ::: "memory")

// ---------- helpers ----------
__device__ __forceinline__ unsigned short f2bf(float f) {
  unsigned u = __float_as_uint(f);
  u += 0x7fffu + ((u >> 16) & 1u);
  return (unsigned short)(u >> 16);
}
__device__ __forceinline__ unsigned encf(float f) {
  unsigned u = __float_as_uint(f);
  return (u & 0x80000000u) ? ~u : (u | 0x80000000u);
}
__device__ __forceinline__ float decf(unsigned u) {
  return (u & 0x80000000u) ? __uint_as_float(u & 0x7fffffffu)
                           : __uint_as_float(~u);
}
// BUILTIN, not inline asm: hand-constraining the accumulator register class
// ("+v" r3-5, "+a" r6) forced allocator data-shuffling around every MFMA
// (16% MfmaUtil) or wholesale spill (r6: 333MB fetch). The builtin lets the
// compiler keep acc natively in AGPRs with zero per-MFMA moves (m97/m201).
__device__ __forceinline__ void mfma_bf16(f32x4& c, s16x8 a, s16x8 b) {
  c = __builtin_amdgcn_mfma_f32_16x16x32_bf16(a, b, c, 0, 0, 0);
}

// stage one 128x64 half-tile: linear LDS dest (global_load_lds requirement),
// inverse-swizzled global source (rule #21). 2 wave-loads per half-tile.
__device__ __forceinline__ void stage_half(const unsigned short* __restrict__ xb,
                                           unsigned short* lds, int rbase,
                                           int row0, int k0, int w, int l) {
#pragma unroll
  for (int i = 0; i < 2; ++i) {
    const int pu = i * 8192 + w * 1024;        // wave-uniform byte offset
    const int p = pu + l * 16;                 // this lane's linear byte
    const int sp = p ^ (((p >> 9) & 1) << 5);  // st_16x32 involution
    const unsigned short* src =
        xb + (size_t)(row0 + (sp >> 7)) * D + k0 + ((sp & 127) >> 1);
    __builtin_amdgcn_global_load_lds(
        (const __attribute__((address_space(1))) void*)src,
        (__attribute__((address_space(3))) void*)(lds + rbase + (pu >> 1)), 16,
        0, 0);
  }
}

__device__ __forceinline__ s16x8 ldfrag(const unsigned short* lds, int rbase,
                                        int r, int c) {
  int b = (r << 7) | (c << 1);
  b ^= ((b >> 9) & 1) << 5;  // same XOR on read side
  return *(const s16x8*)(lds + rbase + (b >> 1));
}

// ---------- kernel 1: L2-normalize rows, write bf16 ----------
__global__ __launch_bounds__(256) void normalize_kernel(
    const float* __restrict__ in, unsigned short* __restrict__ xb) {
  const int row = blockIdx.x;
  const int t = threadIdx.x;
  float4 v = make_float4(0.f, 0.f, 0.f, 0.f);
  const float4* rp = (const float4*)(in + (size_t)row * D);
  if (t < D / 4) v = rp[t];
  float ss = v.x * v.x + v.y * v.y + v.z * v.z + v.w * v.w;
#pragma unroll
  for (int m = 1; m < 64; m <<= 1) ss += __shfl_xor(ss, m, 64);
  __shared__ float wss[4];
  if ((t & 63) == 0) wss[t >> 6] = ss;
  __syncthreads();
  float tot = wss[0] + wss[1] + wss[2] + wss[3];
  float inv = 1.0f / fmaxf(sqrtf(tot), EPSV);
  if (t < D / 4) {
    ushort4 o;
    o.x = f2bf(v.x * inv);
    o.y = f2bf(v.y * inv);
    o.z = f2bf(v.z * inv);
    o.w = f2bf(v.w * inv);
    *(ushort4*)(xb + (size_t)row * D + t * 4) = o;
  }
}

// ---------- kernel 2: 256^2 8-phase triangular Gram + fused row/col max ----
// LDS: 2 buf x {A0,A1,B0,B1} x 16KB = 128KB. 8 waves (2Mx4N), acc 128x64/wave.
__global__ __launch_bounds__(512) void gemm_max_kernel(
    const unsigned short* __restrict__ xb, unsigned* __restrict__ gmax) {
  __shared__ unsigned short lds[65536];
  const int t = threadIdx.x;
  const int w = t >> 6, l = t & 63;
  const int wm = w >> 2, wn = w & 3;

  const int bid = blockIdx.x;
  const int widx = (bid & 7) * (NBLK / 8) + (bid >> 3);  // XCD swizzle
  int brow = (int)((sqrtf(8.0f * (float)widx + 1.0f) - 1.0f) * 0.5f);
  while ((brow + 1) * (brow + 2) / 2 <= widx) ++brow;
  while (brow * (brow + 1) / 2 > widx) --brow;
  const int bcol = widx - brow * (brow + 1) / 2;
  const bool diag = (brow == bcol);
  const int arow = brow * BT, acol = bcol * BT;

  f32x4 acc[8][4] = {};

  const int AB = wm * 8192;                // + buf : this wave's A half
  const int BB = 16384 + (wn >> 1) * 8192; // + buf : this wave's B half

#define RD_B(buf)                                                             \
  {                                                                           \
    _Pragma("unroll") for (int n = 0; n < 4; ++n) _Pragma("unroll") for (     \
        int kk = 0; kk < 2;                                                   \
        ++kk) bfr[n * 2 + kk] = ldfrag(lds, (buf) + BB,                       \
                                       (wn & 1) * 64 + n * 16 + (l & 15),     \
                                       kk * 32 + (l >> 4) * 8);               \
  }
#define RD_A(buf, dst, m0)                                                    \
  {                                                                           \
    _Pragma("unroll") for (int mm = 0; mm < 2; ++mm) _Pragma("unroll") for (  \
        int kk = 0; kk < 2;                                                   \
        ++kk) dst[mm * 2 + kk] = ldfrag(lds, (buf) + AB,                      \
                                        ((m0) + mm) * 16 + (l & 15),          \
                                        kk * 32 + (l >> 4) * 8);              \
  }
#define MFMA_Q(q, a)                                                          \
  {                                                                           \
    __builtin_amdgcn_s_setprio(1);                                            \
    _Pragma("unroll") for (int mm = 0; mm < 2; ++mm)                          \
        _Pragma("unroll") for (int n = 0; n < 4; ++n)                         \
            _Pragma("unroll") for (int kk = 0; kk < 2; ++kk)                  \
                mfma_bf16(acc[2 * (q) + mm][n], a[mm * 2 + kk],               \
                          bfr[n * 2 + kk]);                                   \
    __builtin_amdgcn_s_setprio(0);                                            \
  }

  // prologue: K-tile0 -> buf0 (4 half-tiles), K-tile1 -> buf1.{B0,B1,A0}
  stage_half(xb, lds, 0, arow, 0, w, l);
  stage_half(xb, lds, 8192, arow + 128, 0, w, l);
  stage_half(xb, lds, 16384, acol, 0, w, l);
  stage_half(xb, lds, 24576, acol + 128, 0, w, l);
  VMC(4);
  stage_half(xb, lds, 32768 + 16384, acol, 64, w, l);
  stage_half(xb, lds, 32768 + 24576, acol + 128, 64, w, l);
  stage_half(xb, lds, 32768, arow, 64, w, l);
  VMC(6);
  BARM();

#pragma unroll 1
  for (int itn = 0; itn < 6; ++itn) {
    const int kC1 = 2 * itn + 1;
    const int kS0 = (2 * itn + 2 < 12) ? 2 * itn + 2 : 11;  // buf0 target
    const int kS1 = (2 * itn + 3 < 12) ? 2 * itn + 3 : 11;  // buf1 target
    s16x8 bfr[8], aA[4], aB[4], aC[4], aD[4];

    // ---- phases 1-4: compute K-tile 2t (buf0) ----
    RD_B(0);
    RD_A(0, aA, 0);
    stage_half(xb, lds, 32768 + 8192, arow + 128, kC1 * 64, w, l);  // buf1.A1
    BARM();
    LGKM0();
    MFMA_Q(0, aA);
    BARM();

    RD_A(0, aB, 2);
    RD_A(0, aC, 4);
    stage_half(xb, lds, 16384, acol, kS0 * 64, w, l);  // buf0.B0
    BARM();
    LGKM0();
    MFMA_Q(1, aB);
    BARM();

    RD_A(0, aD, 6);
    stage_half(xb, lds, 24576, acol + 128, kS0 * 64, w, l);  // buf0.B1
    BARM();
    LGKM0();
    MFMA_Q(2, aC);
    BARM();

    stage_half(xb, lds, 0, arow, kS0 * 64, w, l);  // buf0.A0
    BARM();
    LGKM0();
    MFMA_Q(3, aD);
    VMC(6);
    BARM();

    // ---- phases 5-8: compute K-tile 2t+1 (buf1) ----
    RD_B(32768);
    RD_A(32768, aA, 0);
    stage_half(xb, lds, 8192, arow + 128, kS0 * 64, w, l);  // buf0.A1
    BARM();
    LGKM0();
    MFMA_Q(0, aA);
    BARM();

    RD_A(32768, aB, 2);
    RD_A(32768, aC, 4);
    stage_half(xb, lds, 32768 + 16384, acol, kS1 * 64, w, l);  // buf1.B0
    BARM();
    LGKM0();
    MFMA_Q(1, aB);
    BARM();

    RD_A(32768, aD, 6);
    stage_half(xb, lds, 32768 + 24576, acol + 128, kS1 * 64, w, l);  // buf1.B1
    BARM();
    LGKM0();
    MFMA_Q(2, aC);
    BARM();

    stage_half(xb, lds, 32768, arow, kS1 * 64, w, l);  // buf1.A0
    BARM();
    LGKM0();
    MFMA_Q(3, aD);
    VMC(6);
    BARM();
  }

  // ---- epilogue: fused max. C/D: col=lane&15, row=(lane>>4)*4+reg ----
  const int q4 = l >> 4, c0 = l & 15;
  const int rowbase = arow + wm * 128;
  const int colbase = acol + wn * 64;
#pragma unroll
  for (int m = 0; m < 8; ++m) {
#pragma unroll
    for (int reg = 0; reg < 4; ++reg) {
      const int grow = rowbase + m * 16 + q4 * 4 + reg;
      float v = -INFINITY;
#pragma unroll
      for (int n = 0; n < 4; ++n) {
        float val = acc[m][n][reg];
        if (diag && grow == colbase + n * 16 + c0) val = -1.0f;
        v = fmaxf(v, val);
      }
      v = fmaxf(v, __shfl_xor(v, 1));
      v = fmaxf(v, __shfl_xor(v, 2));
      v = fmaxf(v, __shfl_xor(v, 4));
      v = fmaxf(v, __shfl_xor(v, 8));
      if (c0 == 0) atomicMax(&gmax[grow], encf(v));
    }
  }
  if (!diag) {
#pragma unroll
    for (int n = 0; n < 4; ++n) {
      float v = -INFINITY;
#pragma unroll
      for (int m = 0; m < 8; ++m)
#pragma unroll
        for (int reg = 0; reg < 4; ++reg) v = fmaxf(v, acc[m][n][reg]);
      v = fmaxf(v, __shfl_xor(v, 16));
      v = fmaxf(v, __shfl_xor(v, 32));
      if (q4 == 0) atomicMax(&gmax[colbase + n * 16 + c0], encf(v));
    }
  }
  asm volatile("s_waitcnt vmcnt(0)" ::: "memory");  // drain trailing stages
}

// ---------- kernel 3: loss ----------
__global__ __launch_bounds__(1024) void loss_kernel(
    const unsigned* __restrict__ gmax, float* __restrict__ out) {
  const int t = threadIdx.x;
  float s = 0.f;
  for (int i = t; i < NB; i += 1024) {
    float dot = decf(gmax[i]);
    float d2 = fmaxf(2.0f - 2.0f * dot, 0.0f);
    s += logf(sqrtf(d2) + EPSV);
  }
#pragma unroll
  for (int m = 1; m < 64; m <<= 1) s += __shfl_xor(s, m, 64);
  __shared__ float wsum[16];
  if ((t & 63) == 0) wsum[t >> 6] = s;
  __syncthreads();
  if (t == 0) {
    float tot = 0.f;
#pragma unroll
    for (int i = 0; i < 16; ++i) tot += wsum[i];
    out[0] = -tot / (float)NB;
  }
}

// ---------- launch ----------
extern "C" void kernel_launch(void* const* d_in, const int* in_sizes, int n_in,
                              void* d_out, int out_size, void* d_ws,
                              size_t ws_size, hipStream_t stream) {
  const float* in = (const float*)d_in[0];
  float* out = (float*)d_out;
  unsigned* gmax = (unsigned*)d_ws;                             // 8192 u32
  unsigned short* xb = (unsigned short*)((char*)d_ws + 32768);  // bf16 x

  hipMemsetAsync(gmax, 0, NB * sizeof(unsigned), stream);
  normalize_kernel<<<NB, 256, 0, stream>>>(in, xb);
  gemm_max_kernel<<<NBLK, 512, 0, stream>>>(xb, gmax);
  loss_kernel<<<1, 1024, 0, stream>>>(gmax, out);
}

// Round 8
// 127.636 us; speedup vs baseline: 2.6585x; 1.0512x over previous
//
#include <hip/hip_runtime.h>
#include <math.h>

#define NB 8192
#define D 768
#define EPSV 1e-8f
#define BT 256
#define BK 64
#define NT (NB / BT)                 // 32 tiles per dim
#define NBLK (NT * (NT + 1) / 2)     // 528 triangular blocks

typedef float f32x4 __attribute__((ext_vector_type(4)));
typedef short s16x8 __attribute__((ext_vector_type(8)));

#define BARM() asm volatile("s_barrier" ::: "memory")
#define LGKM0() asm volatile("s_waitcnt lgkmcnt(0)" ::: "memory")
#define VMC(n) asm volatile("s_waitcnt vmcnt(" #n ")" ::: "memory")

// ---------- helpers ----------
__device__ __forceinline__ unsigned short f2bf(float f) {
  unsigned u = __float_as_uint(f);
  u += 0x7fffu + ((u >> 16) & 1u);
  return (unsigned short)(u >> 16);
}
__device__ __forceinline__ unsigned encf(float f) {
  unsigned u = __float_as_uint(f);
  return (u & 0x80000000u) ? ~u : (u | 0x80000000u);
}
__device__ __forceinline__ float decf(unsigned u) {
  return (u & 0x80000000u) ? __uint_as_float(u & 0x7fffffffu)
                           : __uint_as_float(~u);
}
__device__ __forceinline__ void mfma_bf16(f32x4& c, s16x8 a, s16x8 b) {
  c = __builtin_amdgcn_mfma_f32_16x16x32_bf16(a, b, c, 0, 0, 0);
}

// Swizzle: granule g -> g ^ (row&7) within each 128B row (8x 16B granules).
// The ldfrag pattern (16 lanes = 16 consecutive rows, same column granule)
// otherwise collides on one 4-bank set (r3-7: one-bit st_16x32 XOR only split
// it 16->8-way; 2000 cyc/phase). This spreads 16 lanes across all 8 granules
// (2/bank = free). Involution, row bits untouched -> rule #21 both-sides OK.
__device__ __forceinline__ int swz(int p) { return p ^ (((p >> 7) & 7) << 4); }

// stage one 128x64 half-tile: linear LDS dest (global_load_lds requirement),
// inverse-swizzled global source (rule #21). 2 wave-loads per half-tile.
__device__ __forceinline__ void stage_half(const unsigned short* __restrict__ xb,
                                           unsigned short* lds, int rbase,
                                           int row0, int k0, int w, int l) {
#pragma unroll
  for (int i = 0; i < 2; ++i) {
    const int pu = i * 8192 + w * 1024;  // wave-uniform byte offset
    const int p = pu + l * 16;           // this lane's linear byte
    const int sp = swz(p);
    const unsigned short* src =
        xb + (size_t)(row0 + (sp >> 7)) * D + k0 + ((sp & 127) >> 1);
    __builtin_amdgcn_global_load_lds(
        (const __attribute__((address_space(1))) void*)src,
        (__attribute__((address_space(3))) void*)(lds + rbase + (pu >> 1)), 16,
        0, 0);
  }
}

__device__ __forceinline__ s16x8 ldfrag(const unsigned short* lds, int rbase,
                                        int r, int c) {
  const int b = swz((r << 7) | (c << 1));
  return *(const s16x8*)(lds + rbase + (b >> 1));
}

// ---------- kernel 1: L2-normalize rows, write bf16 ----------
__global__ __launch_bounds__(256) void normalize_kernel(
    const float* __restrict__ in, unsigned short* __restrict__ xb) {
  const int row = blockIdx.x;
  const int t = threadIdx.x;
  float4 v = make_float4(0.f, 0.f, 0.f, 0.f);
  const float4* rp = (const float4*)(in + (size_t)row * D);
  if (t < D / 4) v = rp[t];
  float ss = v.x * v.x + v.y * v.y + v.z * v.z + v.w * v.w;
#pragma unroll
  for (int m = 1; m < 64; m <<= 1) ss += __shfl_xor(ss, m, 64);
  __shared__ float wss[4];
  if ((t & 63) == 0) wss[t >> 6] = ss;
  __syncthreads();
  float tot = wss[0] + wss[1] + wss[2] + wss[3];
  float inv = 1.0f / fmaxf(sqrtf(tot), EPSV);
  if (t < D / 4) {
    ushort4 o;
    o.x = f2bf(v.x * inv);
    o.y = f2bf(v.y * inv);
    o.z = f2bf(v.z * inv);
    o.w = f2bf(v.w * inv);
    *(ushort4*)(xb + (size_t)row * D + t * 4) = o;
  }
}

// ---------- kernel 2: 256^2 8-phase triangular Gram + fused row/col max ----
// LDS: 2 buf x {A0,A1,B0,B1} x 16KB = 128KB. 8 waves (2Mx4N), acc 128x64/wave.
__global__ __launch_bounds__(512) void gemm_max_kernel(
    const unsigned short* __restrict__ xb, unsigned* __restrict__ gmax) {
  __shared__ unsigned short lds[65536];
  const int t = threadIdx.x;
  const int w = t >> 6, l = t & 63;
  const int wm = w >> 2, wn = w & 3;

  const int bid = blockIdx.x;
  const int widx = (bid & 7) * (NBLK / 8) + (bid >> 3);  // XCD swizzle
  int brow = (int)((sqrtf(8.0f * (float)widx + 1.0f) - 1.0f) * 0.5f);
  while ((brow + 1) * (brow + 2) / 2 <= widx) ++brow;
  while (brow * (brow + 1) / 2 > widx) --brow;
  const int bcol = widx - brow * (brow + 1) / 2;
  const bool diag = (brow == bcol);
  const int arow = brow * BT, acol = bcol * BT;

  f32x4 acc[8][4] = {};

  const int AB = wm * 8192;                // + buf : this wave's A half
  const int BB = 16384 + (wn >> 1) * 8192; // + buf : this wave's B half

#define RD_B(buf)                                                             \
  {                                                                           \
    _Pragma("unroll") for (int n = 0; n < 4; ++n) _Pragma("unroll") for (     \
        int kk = 0; kk < 2;                                                   \
        ++kk) bfr[n * 2 + kk] = ldfrag(lds, (buf) + BB,                       \
                                       (wn & 1) * 64 + n * 16 + (l & 15),     \
                                       kk * 32 + (l >> 4) * 8);               \
  }
#define RD_A(buf, dst, m0)                                                    \
  {                                                                           \
    _Pragma("unroll") for (int mm = 0; mm < 2; ++mm) _Pragma("unroll") for (  \
        int kk = 0; kk < 2;                                                   \
        ++kk) dst[mm * 2 + kk] = ldfrag(lds, (buf) + AB,                      \
                                        ((m0) + mm) * 16 + (l & 15),          \
                                        kk * 32 + (l >> 4) * 8);              \
  }
#define MFMA_Q(q, a)                                                          \
  {                                                                           \
    __builtin_amdgcn_s_setprio(1);                                            \
    _Pragma("unroll") for (int mm = 0; mm < 2; ++mm)                          \
        _Pragma("unroll") for (int n = 0; n < 4; ++n)                         \
            _Pragma("unroll") for (int kk = 0; kk < 2; ++kk)                  \
                mfma_bf16(acc[2 * (q) + mm][n], a[mm * 2 + kk],               \
                          bfr[n * 2 + kk]);                                   \
    __builtin_amdgcn_s_setprio(0);                                            \
  }

  // prologue: K-tile0 -> buf0 (4 half-tiles), K-tile1 -> buf1.{B0,B1,A0}
  stage_half(xb, lds, 0, arow, 0, w, l);
  stage_half(xb, lds, 8192, arow + 128, 0, w, l);
  stage_half(xb, lds, 16384, acol, 0, w, l);
  stage_half(xb, lds, 24576, acol + 128, 0, w, l);
  VMC(4);
  stage_half(xb, lds, 32768 + 16384, acol, 64, w, l);
  stage_half(xb, lds, 32768 + 24576, acol + 128, 64, w, l);
  stage_half(xb, lds, 32768, arow, 64, w, l);
  VMC(6);
  BARM();

#pragma unroll 1
  for (int itn = 0; itn < 6; ++itn) {
    const int kC1 = 2 * itn + 1;
    const int kS0 = (2 * itn + 2 < 12) ? 2 * itn + 2 : 11;  // buf0 target
    const int kS1 = (2 * itn + 3 < 12) ? 2 * itn + 3 : 11;  // buf1 target
    s16x8 bfr[8], aA[4], aB[4], aC[4], aD[4];

    // ---- phases 1-4: compute K-tile 2t (buf0) ----
    RD_B(0);
    RD_A(0, aA, 0);
    stage_half(xb, lds, 32768 + 8192, arow + 128, kC1 * 64, w, l);  // buf1.A1
    BARM();
    LGKM0();
    MFMA_Q(0, aA);
    BARM();

    RD_A(0, aB, 2);
    RD_A(0, aC, 4);
    stage_half(xb, lds, 16384, acol, kS0 * 64, w, l);  // buf0.B0
    BARM();
    LGKM0();
    MFMA_Q(1, aB);
    BARM();

    RD_A(0, aD, 6);
    stage_half(xb, lds, 24576, acol + 128, kS0 * 64, w, l);  // buf0.B1
    BARM();
    LGKM0();
    MFMA_Q(2, aC);
    BARM();

    stage_half(xb, lds, 0, arow, kS0 * 64, w, l);  // buf0.A0
    BARM();
    LGKM0();
    MFMA_Q(3, aD);
    VMC(6);
    BARM();

    // ---- phases 5-8: compute K-tile 2t+1 (buf1) ----
    RD_B(32768);
    RD_A(32768, aA, 0);
    stage_half(xb, lds, 8192, arow + 128, kS0 * 64, w, l);  // buf0.A1
    BARM();
    LGKM0();
    MFMA_Q(0, aA);
    BARM();

    RD_A(32768, aB, 2);
    RD_A(32768, aC, 4);
    stage_half(xb, lds, 32768 + 16384, acol, kS1 * 64, w, l);  // buf1.B0
    BARM();
    LGKM0();
    MFMA_Q(1, aB);
    BARM();

    RD_A(32768, aD, 6);
    stage_half(xb, lds, 32768 + 24576, acol + 128, kS1 * 64, w, l);  // buf1.B1
    BARM();
    LGKM0();
    MFMA_Q(2, aC);
    BARM();

    stage_half(xb, lds, 32768, arow, kS1 * 64, w, l);  // buf1.A0
    BARM();
    LGKM0();
    MFMA_Q(3, aD);
    VMC(6);
    BARM();
  }

  // ---- epilogue: fused max. C/D: col=lane&15, row=(lane>>4)*4+reg ----
  const int q4 = l >> 4, c0 = l & 15;
  const int rowbase = arow + wm * 128;
  const int colbase = acol + wn * 64;
#pragma unroll
  for (int m = 0; m < 8; ++m) {
#pragma unroll
    for (int reg = 0; reg < 4; ++reg) {
      const int grow = rowbase + m * 16 + q4 * 4 + reg;
      float v = -INFINITY;
#pragma unroll
      for (int n = 0; n < 4; ++n) {
        float val = acc[m][n][reg];
        if (diag && grow == colbase + n * 16 + c0) val = -1.0f;
        v = fmaxf(v, val);
      }
      v = fmaxf(v, __shfl_xor(v, 1));
      v = fmaxf(v, __shfl_xor(v, 2));
      v = fmaxf(v, __shfl_xor(v, 4));
      v = fmaxf(v, __shfl_xor(v, 8));
      if (c0 == 0) atomicMax(&gmax[grow], encf(v));
    }
  }
  if (!diag) {
#pragma unroll
    for (int n = 0; n < 4; ++n) {
      float v = -INFINITY;
#pragma unroll
      for (int m = 0; m < 8; ++m)
#pragma unroll
        for (int reg = 0; reg < 4; ++reg) v = fmaxf(v, acc[m][n][reg]);
      v = fmaxf(v, __shfl_xor(v, 16));
      v = fmaxf(v, __shfl_xor(v, 32));
      if (q4 == 0) atomicMax(&gmax[colbase + n * 16 + c0], encf(v));
    }
  }
  asm volatile("s_waitcnt vmcnt(0)" ::: "memory");  // drain trailing stages
}

// ---------- kernel 3: loss ----------
__global__ __launch_bounds__(1024) void loss_kernel(
    const unsigned* __restrict__ gmax, float* __restrict__ out) {
  const int t = threadIdx.x;
  float s = 0.f;
  for (int i = t; i < NB; i += 1024) {
    float dot = decf(gmax[i]);
    float d2 = fmaxf(2.0f - 2.0f * dot, 0.0f);
    s += logf(sqrtf(d2) + EPSV);
  }
#pragma unroll
  for (int m = 1; m < 64; m <<= 1) s += __shfl_xor(s, m, 64);
  __shared__ float wsum[16];
  if ((t & 63) == 0) wsum[t >> 6] = s;
  __syncthreads();
  if (t == 0) {
    float tot = 0.f;
#pragma unroll
    for (int i = 0; i < 16; ++i) tot += wsum[i];
    out[0] = -tot / (float)NB;
  }
}

// ---------- launch ----------
extern "C" void kernel_launch(void* const* d_in, const int* in_sizes, int n_in,
                              void* d_out, int out_size, void* d_ws,
                              size_t ws_size, hipStream_t stream) {
  const float* in = (const float*)d_in[0];
  float* out = (float*)d_out;
  unsigned* gmax = (unsigned*)d_ws;                             // 8192 u32
  unsigned short* xb = (unsigned short*)((char*)d_ws + 32768);  // bf16 x

  hipMemsetAsync(gmax, 0, NB * sizeof(unsigned), stream);
  normalize_kernel<<<NB, 256, 0, stream>>>(in, xb);
  gemm_max_kernel<<<NBLK, 512, 0, stream>>>(xb, gmax);
  loss_kernel<<<1, 1024, 0, stream>>>(gmax, out);
}

// Round 9
// 121.256 us; speedup vs baseline: 2.7984x; 1.0526x over previous
//
#include <hip/hip_runtime.h>
#include <math.h>

#define NB 8192
#define D 768
#define EPSV 1e-8f
#define BT 256
#define BK 64
#define NT (NB / BT)                 // 32 tiles per dim
#define NBLK (NT * (NT + 1) / 2)     // 528 triangular blocks

typedef float f32x4 __attribute__((ext_vector_type(4)));
typedef short s16x8 __attribute__((ext_vector_type(8)));

#define BARM() asm volatile("s_barrier" ::: "memory")
#define LGKM0() asm volatile("s_waitcnt lgkmcnt(0)" ::: "memory")
#define VMC(n) asm volatile("s_waitcnt vmcnt(" #n ")" ::: "memory")

// ---------- helpers ----------
__device__ __forceinline__ unsigned short f2bf(float f) {
  unsigned u = __float_as_uint(f);
  u += 0x7fffu + ((u >> 16) & 1u);
  return (unsigned short)(u >> 16);
}
__device__ __forceinline__ void mfma_bf16(f32x4& c, s16x8 a, s16x8 b) {
  c = __builtin_amdgcn_mfma_f32_16x16x32_bf16(a, b, c, 0, 0, 0);
}

// Swizzle: granule g -> g ^ (row&7) within each 128B row (verified r8:
// SQ_LDS_BANK_CONFLICT 4.87M -> 0). Involution; both-sides (rule #21).
__device__ __forceinline__ int swz(int p) { return p ^ (((p >> 7) & 7) << 4); }

// stage one 128x64 half-tile: linear LDS dest, inverse-swizzled global src.
__device__ __forceinline__ void stage_half(const unsigned short* __restrict__ xb,
                                           unsigned short* lds, int rbase,
                                           int row0, int k0, int w, int l) {
#pragma unroll
  for (int i = 0; i < 2; ++i) {
    const int pu = i * 8192 + w * 1024;  // wave-uniform byte offset
    const int p = pu + l * 16;           // this lane's linear byte
    const int sp = swz(p);
    const unsigned short* src =
        xb + (size_t)(row0 + (sp >> 7)) * D + k0 + ((sp & 127) >> 1);
    __builtin_amdgcn_global_load_lds(
        (const __attribute__((address_space(1))) void*)src,
        (__attribute__((address_space(3))) void*)(lds + rbase + (pu >> 1)), 16,
        0, 0);
  }
}

__device__ __forceinline__ s16x8 ldfrag(const unsigned short* lds, int rbase,
                                        int r, int c) {
  const int b = swz((r << 7) | (c << 1));
  return *(const s16x8*)(lds + rbase + (b >> 1));
}

// ---------- kernel 1: L2-normalize rows, write bf16 ----------
__global__ __launch_bounds__(256) void normalize_kernel(
    const float* __restrict__ in, unsigned short* __restrict__ xb) {
  const int row = blockIdx.x;
  const int t = threadIdx.x;
  float4 v = make_float4(0.f, 0.f, 0.f, 0.f);
  const float4* rp = (const float4*)(in + (size_t)row * D);
  if (t < D / 4) v = rp[t];
  float ss = v.x * v.x + v.y * v.y + v.z * v.z + v.w * v.w;
#pragma unroll
  for (int m = 1; m < 64; m <<= 1) ss += __shfl_xor(ss, m, 64);
  __shared__ float wss[4];
  if ((t & 63) == 0) wss[t >> 6] = ss;
  __syncthreads();
  float tot = wss[0] + wss[1] + wss[2] + wss[3];
  float inv = 1.0f / fmaxf(sqrtf(tot), EPSV);
  if (t < D / 4) {
    ushort4 o;
    o.x = f2bf(v.x * inv);
    o.y = f2bf(v.y * inv);
    o.z = f2bf(v.z * inv);
    o.w = f2bf(v.w * inv);
    *(ushort4*)(xb + (size_t)row * D + t * 4) = o;
  }
}

// ---------- kernel 2: 256^2 8-phase triangular Gram, NO atomics ----------
// Per-tile partial maxes via LDS cross-wave combine -> plain stores:
//   P1[(brow*32+bcol)*256 + r] = row-max of tile     (rows  arow..arow+255)
//   P2[(bcol*32+brow)*256 + c] = col-max of tile     (cols  acol..acol+255)
// r8 evidence: 811k atomicMax x 64B = 52MB of the 77MB FETCH (cross-XCD
// atomics bypass L2); per-block vmcnt(0) drained them serially.
__global__ __launch_bounds__(512) void gemm_max_kernel(
    const unsigned short* __restrict__ xb, float* __restrict__ P1,
    float* __restrict__ P2) {
  __shared__ unsigned short lds[65536];
  const int t = threadIdx.x;
  const int w = t >> 6, l = t & 63;
  const int wm = w >> 2, wn = w & 3;

  const int bid = blockIdx.x;
  const int widx = (bid & 7) * (NBLK / 8) + (bid >> 3);  // XCD swizzle
  int brow = (int)((sqrtf(8.0f * (float)widx + 1.0f) - 1.0f) * 0.5f);
  while ((brow + 1) * (brow + 2) / 2 <= widx) ++brow;
  while (brow * (brow + 1) / 2 > widx) --brow;
  const int bcol = widx - brow * (brow + 1) / 2;
  const bool diag = (brow == bcol);
  const int arow = brow * BT, acol = bcol * BT;

  f32x4 acc[8][4] = {};

  const int AB = wm * 8192;                // + buf : this wave's A half
  const int BB = 16384 + (wn >> 1) * 8192; // + buf : this wave's B half

#define RD_B(buf)                                                             \
  {                                                                           \
    _Pragma("unroll") for (int n = 0; n < 4; ++n) _Pragma("unroll") for (     \
        int kk = 0; kk < 2;                                                   \
        ++kk) bfr[n * 2 + kk] = ldfrag(lds, (buf) + BB,                       \
                                       (wn & 1) * 64 + n * 16 + (l & 15),     \
                                       kk * 32 + (l >> 4) * 8);               \
  }
#define RD_A(buf, dst, m0)                                                    \
  {                                                                           \
    _Pragma("unroll") for (int mm = 0; mm < 2; ++mm) _Pragma("unroll") for (  \
        int kk = 0; kk < 2;                                                   \
        ++kk) dst[mm * 2 + kk] = ldfrag(lds, (buf) + AB,                      \
                                        ((m0) + mm) * 16 + (l & 15),          \
                                        kk * 32 + (l >> 4) * 8);              \
  }
#define MFMA_Q(q, a)                                                          \
  {                                                                           \
    __builtin_amdgcn_s_setprio(1);                                            \
    _Pragma("unroll") for (int mm = 0; mm < 2; ++mm)                          \
        _Pragma("unroll") for (int n = 0; n < 4; ++n)                         \
            _Pragma("unroll") for (int kk = 0; kk < 2; ++kk)                  \
                mfma_bf16(acc[2 * (q) + mm][n], a[mm * 2 + kk],               \
                          bfr[n * 2 + kk]);                                   \
    __builtin_amdgcn_s_setprio(0);                                            \
  }

  // prologue: K-tile0 -> buf0 (4 half-tiles), K-tile1 -> buf1.{B0,B1,A0}
  stage_half(xb, lds, 0, arow, 0, w, l);
  stage_half(xb, lds, 8192, arow + 128, 0, w, l);
  stage_half(xb, lds, 16384, acol, 0, w, l);
  stage_half(xb, lds, 24576, acol + 128, 0, w, l);
  VMC(4);
  stage_half(xb, lds, 32768 + 16384, acol, 64, w, l);
  stage_half(xb, lds, 32768 + 24576, acol + 128, 64, w, l);
  stage_half(xb, lds, 32768, arow, 64, w, l);
  VMC(6);
  BARM();

#pragma unroll 1
  for (int itn = 0; itn < 6; ++itn) {
    const int kC1 = 2 * itn + 1;
    const int kS0 = (2 * itn + 2 < 12) ? 2 * itn + 2 : 11;  // buf0 target
    const int kS1 = (2 * itn + 3 < 12) ? 2 * itn + 3 : 11;  // buf1 target
    s16x8 bfr[8], aA[4], aB[4], aC[4], aD[4];

    // ---- phases 1-4: compute K-tile 2t (buf0) ----
    RD_B(0);
    RD_A(0, aA, 0);
    stage_half(xb, lds, 32768 + 8192, arow + 128, kC1 * 64, w, l);  // buf1.A1
    BARM();
    LGKM0();
    MFMA_Q(0, aA);
    BARM();

    RD_A(0, aB, 2);
    RD_A(0, aC, 4);
    stage_half(xb, lds, 16384, acol, kS0 * 64, w, l);  // buf0.B0
    BARM();
    LGKM0();
    MFMA_Q(1, aB);
    BARM();

    RD_A(0, aD, 6);
    stage_half(xb, lds, 24576, acol + 128, kS0 * 64, w, l);  // buf0.B1
    BARM();
    LGKM0();
    MFMA_Q(2, aC);
    BARM();

    stage_half(xb, lds, 0, arow, kS0 * 64, w, l);  // buf0.A0
    BARM();
    LGKM0();
    MFMA_Q(3, aD);
    VMC(6);
    BARM();

    // ---- phases 5-8: compute K-tile 2t+1 (buf1) ----
    RD_B(32768);
    RD_A(32768, aA, 0);
    stage_half(xb, lds, 8192, arow + 128, kS0 * 64, w, l);  // buf0.A1
    BARM();
    LGKM0();
    MFMA_Q(0, aA);
    BARM();

    RD_A(32768, aB, 2);
    RD_A(32768, aC, 4);
    stage_half(xb, lds, 32768 + 16384, acol, kS1 * 64, w, l);  // buf1.B0
    BARM();
    LGKM0();
    MFMA_Q(1, aB);
    BARM();

    RD_A(32768, aD, 6);
    stage_half(xb, lds, 32768 + 24576, acol + 128, kS1 * 64, w, l);  // buf1.B1
    BARM();
    LGKM0();
    MFMA_Q(2, aC);
    BARM();

    stage_half(xb, lds, 32768, arow, kS1 * 64, w, l);  // buf1.A0
    BARM();
    LGKM0();
    MFMA_Q(3, aD);
    VMC(6);
    BARM();
  }

  // ---- epilogue: cross-wave max combine in LDS, plain stores ----
  VMC(0);   // drain trailing (dead-region) stage writes before LDS reuse
  BARM();
  float* sr = (float*)lds;        // sr[4 wn][256 rows]
  float* sc = sr + 1024;          // sc[2 wm][256 cols]
  const int q4 = l >> 4, c0 = l & 15;

  // row side: per-wave max over its 64-col slice, 16-lane reduce, stash
#pragma unroll
  for (int m = 0; m < 8; ++m) {
#pragma unroll
    for (int reg = 0; reg < 4; ++reg) {
      const int lrow = wm * 128 + m * 16 + q4 * 4 + reg;  // 0..255
      float v = -INFINITY;
#pragma unroll
      for (int n = 0; n < 4; ++n) {
        float val = acc[m][n][reg];
        if (diag && lrow == wn * 64 + n * 16 + c0) val = -1.0f;
        v = fmaxf(v, val);
      }
      v = fmaxf(v, __shfl_xor(v, 1));
      v = fmaxf(v, __shfl_xor(v, 2));
      v = fmaxf(v, __shfl_xor(v, 4));
      v = fmaxf(v, __shfl_xor(v, 8));
      if (c0 == 0) sr[wn * 256 + lrow] = v;
    }
  }
  // col side: per-wave max over its 128-row slice (off-diag only)
  if (!diag) {
#pragma unroll
    for (int n = 0; n < 4; ++n) {
      float v = -INFINITY;
#pragma unroll
      for (int m = 0; m < 8; ++m)
#pragma unroll
        for (int reg = 0; reg < 4; ++reg) v = fmaxf(v, acc[m][n][reg]);
      v = fmaxf(v, __shfl_xor(v, 16));
      v = fmaxf(v, __shfl_xor(v, 32));
      if (q4 == 0) sc[wm * 256 + wn * 64 + n * 16 + c0] = v;
    }
  }
  BARM();
  if (t < 256) {
    const float r = fmaxf(fmaxf(sr[t], sr[256 + t]),
                          fmaxf(sr[512 + t], sr[768 + t]));
    P1[(brow * 32 + bcol) * 256 + t] = r;
    // diag tile: col-max == self-masked row-max by symmetry
    const float c = diag ? r : fmaxf(sc[t], sc[256 + t]);
    P2[(bcol * 32 + brow) * 256 + t] = c;
  }
}

// ---------- kernel 3a: per-row nn-dot max + log-dist partial sums ----------
__global__ __launch_bounds__(256) void rowdist_kernel(
    const float* __restrict__ P1, const float* __restrict__ P2,
    float* __restrict__ psum) {
  const int R = blockIdx.x, j = threadIdx.x;
  float m = -INFINITY;
  for (int c = 0; c <= R; ++c) m = fmaxf(m, P1[(R * 32 + c) * 256 + j]);
  for (int r = R; r < 32; ++r) m = fmaxf(m, P2[(R * 32 + r) * 256 + j]);
  const float d2 = fmaxf(2.0f - 2.0f * m, 0.0f);
  float s = logf(sqrtf(d2) + EPSV);
#pragma unroll
  for (int o = 1; o < 64; o <<= 1) s += __shfl_xor(s, o, 64);
  __shared__ float ws4[4];
  if ((j & 63) == 0) ws4[j >> 6] = s;
  __syncthreads();
  if (j == 0) psum[R] = ws4[0] + ws4[1] + ws4[2] + ws4[3];
}

// ---------- kernel 3b: final loss ----------
__global__ __launch_bounds__(64) void final_kernel(
    const float* __restrict__ psum, float* __restrict__ out) {
  const int l = threadIdx.x;
  float s = (l < 32) ? psum[l] : 0.0f;
#pragma unroll
  for (int o = 1; o < 64; o <<= 1) s += __shfl_xor(s, o, 64);
  if (l == 0) out[0] = -s / (float)NB;
}

// ---------- launch ----------
extern "C" void kernel_launch(void* const* d_in, const int* in_sizes, int n_in,
                              void* d_out, int out_size, void* d_ws,
                              size_t ws_size, hipStream_t stream) {
  const float* in = (const float*)d_in[0];
  float* out = (float*)d_out;
  float* P1 = (float*)d_ws;                 // 32*32*256 f32 = 1 MB
  float* P2 = P1 + 32 * 32 * 256;           // 1 MB
  float* psum = P2 + 32 * 32 * 256;         // 32 f32 (+pad)
  unsigned short* xb = (unsigned short*)(psum + 64);  // bf16 x, 12.6 MB

  normalize_kernel<<<NB, 256, 0, stream>>>(in, xb);
  gemm_max_kernel<<<NBLK, 512, 0, stream>>>(xb, P1, P2);
  rowdist_kernel<<<32, 256, 0, stream>>>(P1, P2, psum);
  final_kernel<<<1, 64, 0, stream>>>(psum, out);
}

// Round 10
// 120.896 us; speedup vs baseline: 2.8067x; 1.0030x over previous
//
#include <hip/hip_runtime.h>
#include <math.h>

#define NB 8192
#define D 768
#define EPSV 1e-8f
#define BT 256
#define BK 64
#define NT (NB / BT)                 // 32 tiles per dim
#define NBLK (NT * (NT + 1) / 2)     // 528 triangular blocks

typedef float f32x4 __attribute__((ext_vector_type(4)));
typedef short s16x8 __attribute__((ext_vector_type(8)));

#define BARM() asm volatile("s_barrier" ::: "memory")
#define LGKM0() asm volatile("s_waitcnt lgkmcnt(0)" ::: "memory")
#define VMC(n) asm volatile("s_waitcnt vmcnt(" #n ")" ::: "memory")

// ---------- helpers ----------
__device__ __forceinline__ unsigned short f2bf(float f) {
  unsigned u = __float_as_uint(f);
  u += 0x7fffu + ((u >> 16) & 1u);
  return (unsigned short)(u >> 16);
}
__device__ __forceinline__ void mfma_bf16(f32x4& c, s16x8 a, s16x8 b) {
  c = __builtin_amdgcn_mfma_f32_16x16x32_bf16(a, b, c, 0, 0, 0);
}

// Swizzle: granule g -> g ^ (row&7) within each 128B row (verified r8:
// SQ_LDS_BANK_CONFLICT 4.87M -> 0). Involution; both-sides (rule #21).
__device__ __forceinline__ int swz(int p) { return p ^ (((p >> 7) & 7) << 4); }

// stage one 128x64 half-tile: linear LDS dest, inverse-swizzled global src.
__device__ __forceinline__ void stage_half(const unsigned short* __restrict__ xb,
                                           unsigned short* lds, int rbase,
                                           int row0, int k0, int w, int l) {
#pragma unroll
  for (int i = 0; i < 2; ++i) {
    const int pu = i * 8192 + w * 1024;  // wave-uniform byte offset
    const int p = pu + l * 16;           // this lane's linear byte
    const int sp = swz(p);
    const unsigned short* src =
        xb + (size_t)(row0 + (sp >> 7)) * D + k0 + ((sp & 127) >> 1);
    __builtin_amdgcn_global_load_lds(
        (const __attribute__((address_space(1))) void*)src,
        (__attribute__((address_space(3))) void*)(lds + rbase + (pu >> 1)), 16,
        0, 0);
  }
}

__device__ __forceinline__ s16x8 ldfrag(const unsigned short* lds, int rbase,
                                        int r, int c) {
  const int b = swz((r << 7) | (c << 1));
  return *(const s16x8*)(lds + rbase + (b >> 1));
}

// ---------- kernel 1: L2-normalize rows, write bf16 ----------
__global__ __launch_bounds__(256) void normalize_kernel(
    const float* __restrict__ in, unsigned short* __restrict__ xb) {
  const int row = blockIdx.x;
  const int t = threadIdx.x;
  float4 v = make_float4(0.f, 0.f, 0.f, 0.f);
  const float4* rp = (const float4*)(in + (size_t)row * D);
  if (t < D / 4) v = rp[t];
  float ss = v.x * v.x + v.y * v.y + v.z * v.z + v.w * v.w;
#pragma unroll
  for (int m = 1; m < 64; m <<= 1) ss += __shfl_xor(ss, m, 64);
  __shared__ float wss[4];
  if ((t & 63) == 0) wss[t >> 6] = ss;
  __syncthreads();
  float tot = wss[0] + wss[1] + wss[2] + wss[3];
  float inv = 1.0f / fmaxf(sqrtf(tot), EPSV);
  if (t < D / 4) {
    ushort4 o;
    o.x = f2bf(v.x * inv);
    o.y = f2bf(v.y * inv);
    o.z = f2bf(v.z * inv);
    o.w = f2bf(v.w * inv);
    *(ushort4*)(xb + (size_t)row * D + t * 4) = o;
  }
}

// ---------- kernel 2: 256^2 single-barrier-phase triangular Gram ----------
// r9 change: drop the mid-phase BARM+LGKM0 (was serializing LDS-drain vs
// MFMA windows: 1725 cyc/phase vs ~825 achievable). Compiler-visible ds_reads
// get counted lgkmcnt before each MFMA -> waves slip, LDS overlaps MFMA.
// Explicit LGKM0 kept ONLY at end of ph3/ph7 (aD read ph3/7, consumed ph4/8,
// its region A0 staged ph4/8 -> must complete before that stage issues).
__global__ __launch_bounds__(512) void gemm_max_kernel(
    const unsigned short* __restrict__ xb, float* __restrict__ P1,
    float* __restrict__ P2) {
  __shared__ unsigned short lds[65536];
  const int t = threadIdx.x;
  const int w = t >> 6, l = t & 63;
  const int wm = w >> 2, wn = w & 3;

  const int bid = blockIdx.x;
  const int widx = (bid & 7) * (NBLK / 8) + (bid >> 3);  // XCD swizzle
  int brow = (int)((sqrtf(8.0f * (float)widx + 1.0f) - 1.0f) * 0.5f);
  while ((brow + 1) * (brow + 2) / 2 <= widx) ++brow;
  while (brow * (brow + 1) / 2 > widx) --brow;
  const int bcol = widx - brow * (brow + 1) / 2;
  const bool diag = (brow == bcol);
  const int arow = brow * BT, acol = bcol * BT;

  f32x4 acc[8][4] = {};

  const int AB = wm * 8192;                // + buf : this wave's A half
  const int BB = 16384 + (wn >> 1) * 8192; // + buf : this wave's B half

#define RD_B(buf)                                                             \
  {                                                                           \
    _Pragma("unroll") for (int n = 0; n < 4; ++n) _Pragma("unroll") for (     \
        int kk = 0; kk < 2;                                                   \
        ++kk) bfr[n * 2 + kk] = ldfrag(lds, (buf) + BB,                       \
                                       (wn & 1) * 64 + n * 16 + (l & 15),     \
                                       kk * 32 + (l >> 4) * 8);               \
  }
#define RD_A(buf, dst, m0)                                                    \
  {                                                                           \
    _Pragma("unroll") for (int mm = 0; mm < 2; ++mm) _Pragma("unroll") for (  \
        int kk = 0; kk < 2;                                                   \
        ++kk) dst[mm * 2 + kk] = ldfrag(lds, (buf) + AB,                      \
                                        ((m0) + mm) * 16 + (l & 15),          \
                                        kk * 32 + (l >> 4) * 8);              \
  }
#define MFMA_Q(q, a)                                                          \
  {                                                                           \
    __builtin_amdgcn_s_setprio(1);                                            \
    _Pragma("unroll") for (int mm = 0; mm < 2; ++mm)                          \
        _Pragma("unroll") for (int n = 0; n < 4; ++n)                         \
            _Pragma("unroll") for (int kk = 0; kk < 2; ++kk)                  \
                mfma_bf16(acc[2 * (q) + mm][n], a[mm * 2 + kk],               \
                          bfr[n * 2 + kk]);                                   \
    __builtin_amdgcn_s_setprio(0);                                            \
  }

  // prologue: K-tile0 -> buf0 (4 half-tiles), K-tile1 -> buf1.{B0,B1,A0}
  stage_half(xb, lds, 0, arow, 0, w, l);
  stage_half(xb, lds, 8192, arow + 128, 0, w, l);
  stage_half(xb, lds, 16384, acol, 0, w, l);
  stage_half(xb, lds, 24576, acol + 128, 0, w, l);
  VMC(4);
  stage_half(xb, lds, 32768 + 16384, acol, 64, w, l);
  stage_half(xb, lds, 32768 + 24576, acol + 128, 64, w, l);
  stage_half(xb, lds, 32768, arow, 64, w, l);
  VMC(6);
  BARM();

#pragma unroll 1
  for (int itn = 0; itn < 6; ++itn) {
    const int kC1 = 2 * itn + 1;
    const int kS0 = (2 * itn + 2 < 12) ? 2 * itn + 2 : 11;  // buf0 target
    const int kS1 = (2 * itn + 3 < 12) ? 2 * itn + 3 : 11;  // buf1 target
    s16x8 bfr[8], aA[4], aB[4], aC[4], aD[4];

    // ---- phases 1-4: compute K-tile 2t (buf0) ----
    RD_B(0);
    RD_A(0, aA, 0);
    stage_half(xb, lds, 32768 + 8192, arow + 128, kC1 * 64, w, l);  // buf1.A1
    MFMA_Q(0, aA);
    BARM();

    RD_A(0, aB, 2);
    RD_A(0, aC, 4);
    stage_half(xb, lds, 16384, acol, kS0 * 64, w, l);  // buf0.B0
    MFMA_Q(1, aB);
    BARM();

    RD_A(0, aD, 6);
    stage_half(xb, lds, 24576, acol + 128, kS0 * 64, w, l);  // buf0.B1
    MFMA_Q(2, aC);
    LGKM0();  // aD complete before ph4 stages A0
    BARM();

    stage_half(xb, lds, 0, arow, kS0 * 64, w, l);  // buf0.A0
    MFMA_Q(3, aD);
    VMC(6);
    BARM();

    // ---- phases 5-8: compute K-tile 2t+1 (buf1) ----
    RD_B(32768);
    RD_A(32768, aA, 0);
    stage_half(xb, lds, 8192, arow + 128, kS0 * 64, w, l);  // buf0.A1
    MFMA_Q(0, aA);
    BARM();

    RD_A(32768, aB, 2);
    RD_A(32768, aC, 4);
    stage_half(xb, lds, 32768 + 16384, acol, kS1 * 64, w, l);  // buf1.B0
    MFMA_Q(1, aB);
    BARM();

    RD_A(32768, aD, 6);
    stage_half(xb, lds, 32768 + 24576, acol + 128, kS1 * 64, w, l);  // buf1.B1
    MFMA_Q(2, aC);
    LGKM0();  // aD complete before ph8 stages buf1.A0
    BARM();

    stage_half(xb, lds, 32768, arow, kS1 * 64, w, l);  // buf1.A0
    MFMA_Q(3, aD);
    VMC(6);
    BARM();
  }

  // ---- epilogue: cross-wave max combine in LDS, plain stores ----
  VMC(0);   // drain trailing (dead-region) stage writes before LDS reuse
  BARM();
  float* sr = (float*)lds;        // sr[4 wn][256 rows]
  float* sc = sr + 1024;          // sc[2 wm][256 cols]
  const int q4 = l >> 4, c0 = l & 15;

  // row side: per-wave max over its 64-col slice, 16-lane reduce, stash
#pragma unroll
  for (int m = 0; m < 8; ++m) {
#pragma unroll
    for (int reg = 0; reg < 4; ++reg) {
      const int lrow = wm * 128 + m * 16 + q4 * 4 + reg;  // 0..255
      float v = -INFINITY;
#pragma unroll
      for (int n = 0; n < 4; ++n) {
        float val = acc[m][n][reg];
        if (diag && lrow == wn * 64 + n * 16 + c0) val = -1.0f;
        v = fmaxf(v, val);
      }
      v = fmaxf(v, __shfl_xor(v, 1));
      v = fmaxf(v, __shfl_xor(v, 2));
      v = fmaxf(v, __shfl_xor(v, 4));
      v = fmaxf(v, __shfl_xor(v, 8));
      if (c0 == 0) sr[wn * 256 + lrow] = v;
    }
  }
  // col side: per-wave max over its 128-row slice (off-diag only)
  if (!diag) {
#pragma unroll
    for (int n = 0; n < 4; ++n) {
      float v = -INFINITY;
#pragma unroll
      for (int m = 0; m < 8; ++m)
#pragma unroll
        for (int reg = 0; reg < 4; ++reg) v = fmaxf(v, acc[m][n][reg]);
      v = fmaxf(v, __shfl_xor(v, 16));
      v = fmaxf(v, __shfl_xor(v, 32));
      if (q4 == 0) sc[wm * 256 + wn * 64 + n * 16 + c0] = v;
    }
  }
  BARM();
  if (t < 256) {
    const float r = fmaxf(fmaxf(sr[t], sr[256 + t]),
                          fmaxf(sr[512 + t], sr[768 + t]));
    P1[(brow * 32 + bcol) * 256 + t] = r;
    // diag tile: col-max == self-masked row-max by symmetry
    const float c = diag ? r : fmaxf(sc[t], sc[256 + t]);
    P2[(bcol * 32 + brow) * 256 + t] = c;
  }
}

// ---------- kernel 3a: per-row nn-dot max + log-dist partial sums ----------
__global__ __launch_bounds__(256) void rowdist_kernel(
    const float* __restrict__ P1, const float* __restrict__ P2,
    float* __restrict__ psum) {
  const int R = blockIdx.x, j = threadIdx.x;
  float m = -INFINITY;
  for (int c = 0; c <= R; ++c) m = fmaxf(m, P1[(R * 32 + c) * 256 + j]);
  for (int r = R; r < 32; ++r) m = fmaxf(m, P2[(R * 32 + r) * 256 + j]);
  const float d2 = fmaxf(2.0f - 2.0f * m, 0.0f);
  float s = logf(sqrtf(d2) + EPSV);
#pragma unroll
  for (int o = 1; o < 64; o <<= 1) s += __shfl_xor(s, o, 64);
  __shared__ float ws4[4];
  if ((j & 63) == 0) ws4[j >> 6] = s;
  __syncthreads();
  if (j == 0) psum[R] = ws4[0] + ws4[1] + ws4[2] + ws4[3];
}

// ---------- kernel 3b: final loss ----------
__global__ __launch_bounds__(64) void final_kernel(
    const float* __restrict__ psum, float* __restrict__ out) {
  const int l = threadIdx.x;
  float s = (l < 32) ? psum[l] : 0.0f;
#pragma unroll
  for (int o = 1; o < 64; o <<= 1) s += __shfl_xor(s, o, 64);
  if (l == 0) out[0] = -s / (float)NB;
}

// ---------- launch ----------
extern "C" void kernel_launch(void* const* d_in, const int* in_sizes, int n_in,
                              void* d_out, int out_size, void* d_ws,
                              size_t ws_size, hipStream_t stream) {
  const float* in = (const float*)d_in[0];
  float* out = (float*)d_out;
  float* P1 = (float*)d_ws;                 // 32*32*256 f32 = 1 MB
  float* P2 = P1 + 32 * 32 * 256;           // 1 MB
  float* psum = P2 + 32 * 32 * 256;         // 32 f32 (+pad)
  unsigned short* xb = (unsigned short*)(psum + 64);  // bf16 x, 12.6 MB

  normalize_kernel<<<NB, 256, 0, stream>>>(in, xb);
  gemm_max_kernel<<<NBLK, 512, 0, stream>>>(xb, P1, P2);
  rowdist_kernel<<<32, 256, 0, stream>>>(P1, P2, psum);
  final_kernel<<<1, 64, 0, stream>>>(psum, out);
}